// Round 1
// 214.590 us; speedup vs baseline: 1.1307x; 1.1307x over previous
//
#include <hip/hip_runtime.h>

#define N_NODES 50000
#define N_EDGES 800000
#define IN_DIM 256
#define HID_DIM 128
#define OUT_DIM 64
#define CAP 64      // per-node bucket capacity; deg ~Binomial(800k,1/50k), max over 50k ~35

// two-phase binning
#define K_BINS 256
#define NPB 196     // nodes per bin: 256*196 = 50176 >= 50000
#define BINCAP 4096 // expected 3125/bin, sigma ~56 -> 17-sigma headroom
#define CHUNK 4096  // edges per k_bin workgroup
#define N_BINWG 196 // ceil(800000/4096)

typedef __bf16 bf16x8 __attribute__((ext_vector_type(8)));
typedef float f32x4 __attribute__((ext_vector_type(4)));
typedef unsigned short u16x8 __attribute__((ext_vector_type(8)));
typedef unsigned short ushort_t;
typedef unsigned int uint_t;

// float -> bf16 bits, round-to-nearest-even (finite values)
__device__ __forceinline__ ushort_t f2bf(float f) {
    uint_t u = __float_as_uint(f);
    return (ushort_t)((u + 0x7fffu + ((u >> 16) & 1u)) >> 16);
}
__device__ __forceinline__ float bf_lo(uint_t u) { return __uint_as_float(u << 16); }
__device__ __forceinline__ float bf_hi(uint_t u) { return __uint_as_float(u & 0xffff0000u); }

// ---------------- launch 2: cast/transpose weights ----------------
__global__ __launch_bounds__(256) void k_init(const float* __restrict__ W1,
                                              ushort_t* __restrict__ w1t,
                                              const float* __restrict__ W2,
                                              ushort_t* __restrict__ w2t) {
    const int bid = blockIdx.x;
    const int t = threadIdx.x;
    if (bid < 128) {                       // W1 [256x128] -> w1t [128x256] bf16
        int id = bid * 256 + t;
        int k = id >> 7, c = id & 127;
        w1t[c * IN_DIM + k] = f2bf(W1[id]);
    } else {                               // W2 [128x64] -> w2t [64x128] bf16
        int id = (bid - 128) * 256 + t;
        int k = id >> 6, c = id & 63;
        w2t[c * HID_DIM + k] = f2bf(W2[id]);
    }
}

// ---------------- launch 3a: bin edges by dst range ----------------
// Replaces scatter-to-es bucketing (44.7 MB partial-line writeback, 49 us).
// Each wg: LDS histogram over 256 bins -> one global atomic per bin ->
// dense append of packed (dst_local<<16 | src) records to per-bin streams.
// Register arrays are statically indexed (unrolled 16) to stay out of scratch.
__global__ __launch_bounds__(256) void k_bin(const int* __restrict__ srcs,
                                             const int* __restrict__ dsts,
                                             int* __restrict__ bin_cur,
                                             uint_t* __restrict__ binbuf) {
    __shared__ int lcnt[K_BINS];
    __shared__ int lbase[K_BINS];
    const int t = threadIdx.x;
    lcnt[t] = 0;
    __syncthreads();
    const int start = blockIdx.x * CHUNK;
    int b_[16]; int p_[16]; uint_t rec_[16];
#pragma unroll
    for (int k = 0; k < 16; ++k) {
        int e = start + t + k * 256;
        bool ok = (e < N_EDGES);
        int d = ok ? dsts[e] : 0;
        int s = ok ? srcs[e] : 0;
        int b = d / NPB;                       // magic-mul, NPB is compile-time
        b_[k] = ok ? b : -1;
        p_[k] = ok ? atomicAdd(&lcnt[b], 1) : 0;
        rec_[k] = (uint_t)s | ((uint_t)(d - b * NPB) << 16);  // src < 65536, dl < 196
    }
    __syncthreads();
    lbase[t] = atomicAdd(&bin_cur[t], lcnt[t]);   // 256 atomics/wg, 196 wgs total
    __syncthreads();
#pragma unroll
    for (int k = 0; k < 16; ++k) {
        if (b_[k] >= 0) {
            int pos = lbase[b_[k]] + p_[k];
            if (pos < BINCAP) binbuf[(size_t)b_[k] * BINCAP + pos] = rec_[k];
        }
    }
}

// ---------------- launch 3b: fill es buckets, one wg per bin ----------------
// Bin's whole es region (196 nodes x 128 B = 25 KB) staged in LDS: all scatter
// happens in LDS, HBM sees one dense coalesced 25 KB write per bin.
// deg comes from the LDS counters -> dinv/ndeg written here (removed from gemm1).
__global__ __launch_bounds__(256) void k_fill(const int* __restrict__ bin_cur,
                                              const uint_t* __restrict__ binbuf,
                                              ushort_t* __restrict__ es,
                                              float* __restrict__ dinv,
                                              int* __restrict__ ndeg) {
    __shared__ int cnt[NPB];
    __shared__ __align__(16) ushort_t pay[NPB][CAP];   // 25088 B
    const int b = blockIdx.x, t = threadIdx.x;
    if (t < NPB) cnt[t] = 0;
    __syncthreads();
    const int n = min(bin_cur[b], BINCAP);
    const uint_t* rec = binbuf + (size_t)b * BINCAP;
    for (int e = t; e < n; e += 256) {
        uint_t r = rec[e];
        int dl = r >> 16;
        int p = atomicAdd(&cnt[dl], 1);
        if (p < CAP) pay[dl][p] = (ushort_t)(r & 0xffffu);
    }
    __syncthreads();
    // dense dump: 25088 B as 1568 x uint4 (slots past deg are never read)
    uint4* gdst = (uint4*)(es + (size_t)b * NPB * CAP);
    const uint4* lsrc = (const uint4*)&pay[0][0];
    for (int i = t; i < NPB * CAP / 8; i += 256) gdst[i] = lsrc[i];
    if (t < NPB) {
        int node = b * NPB + t;
        if (node < N_NODES) {
            int deg = cnt[t];
            dinv[node] = rsqrtf((float)(deg + 1));
            ndeg[node] = min(deg, CAP);
        }
    }
}

// ---------------- launch 4: gemm1 (MFMA): hb(bf16) = x @ W1 ----------------
__global__ __launch_bounds__(64) void k_gemm1(const float* __restrict__ x,
                                              const ushort_t* __restrict__ w1t,
                                              ushort_t* __restrict__ hb) {
    const int lane = threadIdx.x;
    const int l15 = lane & 15, quad = lane >> 4;
    const int row = blockIdx.x * 16 + l15;
    f32x4 acc[8];
#pragma unroll
    for (int n = 0; n < 8; ++n) acc[n] = (f32x4){0.f, 0.f, 0.f, 0.f};
    const float* xrow = x + (size_t)row * IN_DIM + quad * 8;
    const ushort_t* wbase = w1t + quad * 8;
#pragma unroll
    for (int t = 0; t < 8; ++t) {
        const float4* xp = (const float4*)(xrow + t * 32);
        float4 f0 = xp[0], f1 = xp[1];
        u16x8 au;
        au[0] = f2bf(f0.x); au[1] = f2bf(f0.y); au[2] = f2bf(f0.z); au[3] = f2bf(f0.w);
        au[4] = f2bf(f1.x); au[5] = f2bf(f1.y); au[6] = f2bf(f1.z); au[7] = f2bf(f1.w);
        bf16x8 a = __builtin_bit_cast(bf16x8, au);
#pragma unroll
        for (int n = 0; n < 8; ++n) {
            bf16x8 b = *(const bf16x8*)(wbase + (n * 16 + l15) * IN_DIM + t * 32);
            acc[n] = __builtin_amdgcn_mfma_f32_16x16x32_bf16(a, b, acc[n], 0, 0, 0);
        }
    }
    // C/D layout: col = lane&15, row = quad*4 + r  [measured m89/m91]
    ushort_t* hrow = hb + ((size_t)blockIdx.x * 16 + quad * 4) * HID_DIM + l15;
#pragma unroll
    for (int n = 0; n < 8; ++n)
#pragma unroll
        for (int r = 0; r < 4; ++r)
            hrow[(size_t)r * HID_DIM + n * 16] = f2bf(acc[n][r]);
}

// ---------------- launch 5: agg1 ----------------
__global__ __launch_bounds__(256) void k_agg1(const ushort_t* __restrict__ hb,
                                              const int* __restrict__ ndeg,
                                              const float* __restrict__ dinv,
                                              const ushort_t* __restrict__ es,
                                              const float* __restrict__ b,
                                              ushort_t* __restrict__ hrelu) {
    const int i = blockIdx.x * 4 + (threadIdx.x >> 6);   // 12500*4 = 50000 exact
    const int lane = threadIdx.x & 63;
    const float dv = dinv[i];
    const int n = ndeg[i];
    int   sj = 0;
    float nmj = 0.f;
    if (lane < n) {
        sj = (int)es[i * CAP + lane];
        nmj = dinv[sj] * dv;
    }
    uint_t u = *(const uint_t*)(hb + (size_t)i * HID_DIM + 2 * lane);
    float a0 = bf_lo(u) * dv * dv;                       // self loop
    float a1 = bf_hi(u) * dv * dv;
    int j = 0;
    for (; j + 8 <= n; j += 8) {
        int s0 = __shfl(sj, j),     s1 = __shfl(sj, j + 1);
        int s2 = __shfl(sj, j + 2), s3 = __shfl(sj, j + 3);
        int s4 = __shfl(sj, j + 4), s5 = __shfl(sj, j + 5);
        int s6 = __shfl(sj, j + 6), s7 = __shfl(sj, j + 7);
        float m0 = __shfl(nmj, j),     m1 = __shfl(nmj, j + 1);
        float m2 = __shfl(nmj, j + 2), m3 = __shfl(nmj, j + 3);
        float m4 = __shfl(nmj, j + 4), m5 = __shfl(nmj, j + 5);
        float m6 = __shfl(nmj, j + 6), m7 = __shfl(nmj, j + 7);
        uint_t v0 = *(const uint_t*)(hb + (size_t)s0 * HID_DIM + 2 * lane);
        uint_t v1 = *(const uint_t*)(hb + (size_t)s1 * HID_DIM + 2 * lane);
        uint_t v2 = *(const uint_t*)(hb + (size_t)s2 * HID_DIM + 2 * lane);
        uint_t v3 = *(const uint_t*)(hb + (size_t)s3 * HID_DIM + 2 * lane);
        uint_t v4 = *(const uint_t*)(hb + (size_t)s4 * HID_DIM + 2 * lane);
        uint_t v5 = *(const uint_t*)(hb + (size_t)s5 * HID_DIM + 2 * lane);
        uint_t v6 = *(const uint_t*)(hb + (size_t)s6 * HID_DIM + 2 * lane);
        uint_t v7 = *(const uint_t*)(hb + (size_t)s7 * HID_DIM + 2 * lane);
        a0 += bf_lo(v0) * m0 + bf_lo(v1) * m1 + bf_lo(v2) * m2 + bf_lo(v3) * m3
            + bf_lo(v4) * m4 + bf_lo(v5) * m5 + bf_lo(v6) * m6 + bf_lo(v7) * m7;
        a1 += bf_hi(v0) * m0 + bf_hi(v1) * m1 + bf_hi(v2) * m2 + bf_hi(v3) * m3
            + bf_hi(v4) * m4 + bf_hi(v5) * m5 + bf_hi(v6) * m6 + bf_hi(v7) * m7;
    }
    for (; j + 4 <= n; j += 4) {
        int s0 = __shfl(sj, j),     s1 = __shfl(sj, j + 1);
        int s2 = __shfl(sj, j + 2), s3 = __shfl(sj, j + 3);
        float m0 = __shfl(nmj, j),     m1 = __shfl(nmj, j + 1);
        float m2 = __shfl(nmj, j + 2), m3 = __shfl(nmj, j + 3);
        uint_t v0 = *(const uint_t*)(hb + (size_t)s0 * HID_DIM + 2 * lane);
        uint_t v1 = *(const uint_t*)(hb + (size_t)s1 * HID_DIM + 2 * lane);
        uint_t v2 = *(const uint_t*)(hb + (size_t)s2 * HID_DIM + 2 * lane);
        uint_t v3 = *(const uint_t*)(hb + (size_t)s3 * HID_DIM + 2 * lane);
        a0 += bf_lo(v0) * m0 + bf_lo(v1) * m1 + bf_lo(v2) * m2 + bf_lo(v3) * m3;
        a1 += bf_hi(v0) * m0 + bf_hi(v1) * m1 + bf_hi(v2) * m2 + bf_hi(v3) * m3;
    }
    for (; j < n; ++j) {
        int s = __shfl(sj, j);
        float nm = __shfl(nmj, j);
        uint_t v = *(const uint_t*)(hb + (size_t)s * HID_DIM + 2 * lane);
        a0 += bf_lo(v) * nm;
        a1 += bf_hi(v) * nm;
    }
    float v0 = a0 + b[2 * lane];     v0 = v0 > 0.f ? v0 : 0.f;
    float v1 = a1 + b[2 * lane + 1]; v1 = v1 > 0.f ? v1 : 0.f;
    *(uint_t*)(hrelu + (size_t)i * HID_DIM + 2 * lane) = ((uint_t)f2bf(v1) << 16) | f2bf(v0);
}

// ---------------- launch 6: gemm2 (MFMA): h2(bf16) = hrelu @ W2 ----------------
__global__ __launch_bounds__(64) void k_gemm2(const ushort_t* __restrict__ hrelu,
                                              const ushort_t* __restrict__ w2t,
                                              ushort_t* __restrict__ h2) {
    const int lane = threadIdx.x;
    const int l15 = lane & 15, quad = lane >> 4;
    const int row = blockIdx.x * 16 + l15;
    f32x4 acc[4];
#pragma unroll
    for (int n = 0; n < 4; ++n) acc[n] = (f32x4){0.f, 0.f, 0.f, 0.f};
    const ushort_t* arow = hrelu + (size_t)row * HID_DIM + quad * 8;
    const ushort_t* wbase = w2t + quad * 8;
#pragma unroll
    for (int t = 0; t < 4; ++t) {
        bf16x8 a = *(const bf16x8*)(arow + t * 32);
#pragma unroll
        for (int n = 0; n < 4; ++n) {
            bf16x8 b = *(const bf16x8*)(wbase + (n * 16 + l15) * HID_DIM + t * 32);
            acc[n] = __builtin_amdgcn_mfma_f32_16x16x32_bf16(a, b, acc[n], 0, 0, 0);
        }
    }
    ushort_t* orow = h2 + ((size_t)blockIdx.x * 16 + quad * 4) * OUT_DIM + l15;
#pragma unroll
    for (int n = 0; n < 4; ++n)
#pragma unroll
        for (int r = 0; r < 4; ++r)
            orow[(size_t)r * OUT_DIM + n * 16] = f2bf(acc[n][r]);
}

// ---------------- launch 7: agg2: out(fp32) = D^-1/2 (A+I) D^-1/2 h2 + b2 ----------------
__global__ __launch_bounds__(256) void k_agg2(const ushort_t* __restrict__ h2,
                                              const int* __restrict__ ndeg,
                                              const float* __restrict__ dinv,
                                              const ushort_t* __restrict__ es,
                                              const float* __restrict__ b,
                                              float* __restrict__ out) {
    const int i = blockIdx.x * 4 + (threadIdx.x >> 6);
    const int lane = threadIdx.x & 63;
    const float dv = dinv[i];
    const int n = ndeg[i];
    int   sj = 0;
    float nmj = 0.f;
    if (lane < n) {
        sj = (int)es[i * CAP + lane];
        nmj = dinv[sj] * dv;
    }
    float acc = __uint_as_float(((uint_t)h2[(size_t)i * OUT_DIM + lane]) << 16) * dv * dv;
    int j = 0;
    for (; j + 8 <= n; j += 8) {
        int s0 = __shfl(sj, j),     s1 = __shfl(sj, j + 1);
        int s2 = __shfl(sj, j + 2), s3 = __shfl(sj, j + 3);
        int s4 = __shfl(sj, j + 4), s5 = __shfl(sj, j + 5);
        int s6 = __shfl(sj, j + 6), s7 = __shfl(sj, j + 7);
        float m0 = __shfl(nmj, j),     m1 = __shfl(nmj, j + 1);
        float m2 = __shfl(nmj, j + 2), m3 = __shfl(nmj, j + 3);
        float m4 = __shfl(nmj, j + 4), m5 = __shfl(nmj, j + 5);
        float m6 = __shfl(nmj, j + 6), m7 = __shfl(nmj, j + 7);
        float v0 = __uint_as_float(((uint_t)h2[(size_t)s0 * OUT_DIM + lane]) << 16);
        float v1 = __uint_as_float(((uint_t)h2[(size_t)s1 * OUT_DIM + lane]) << 16);
        float v2 = __uint_as_float(((uint_t)h2[(size_t)s2 * OUT_DIM + lane]) << 16);
        float v3 = __uint_as_float(((uint_t)h2[(size_t)s3 * OUT_DIM + lane]) << 16);
        float v4 = __uint_as_float(((uint_t)h2[(size_t)s4 * OUT_DIM + lane]) << 16);
        float v5 = __uint_as_float(((uint_t)h2[(size_t)s5 * OUT_DIM + lane]) << 16);
        float v6 = __uint_as_float(((uint_t)h2[(size_t)s6 * OUT_DIM + lane]) << 16);
        float v7 = __uint_as_float(((uint_t)h2[(size_t)s7 * OUT_DIM + lane]) << 16);
        acc += v0 * m0 + v1 * m1 + v2 * m2 + v3 * m3 + v4 * m4 + v5 * m5 + v6 * m6 + v7 * m7;
    }
    for (; j + 4 <= n; j += 4) {
        int s0 = __shfl(sj, j),     s1 = __shfl(sj, j + 1);
        int s2 = __shfl(sj, j + 2), s3 = __shfl(sj, j + 3);
        float m0 = __shfl(nmj, j),     m1 = __shfl(nmj, j + 1);
        float m2 = __shfl(nmj, j + 2), m3 = __shfl(nmj, j + 3);
        float v0 = __uint_as_float(((uint_t)h2[(size_t)s0 * OUT_DIM + lane]) << 16);
        float v1 = __uint_as_float(((uint_t)h2[(size_t)s1 * OUT_DIM + lane]) << 16);
        float v2 = __uint_as_float(((uint_t)h2[(size_t)s2 * OUT_DIM + lane]) << 16);
        float v3 = __uint_as_float(((uint_t)h2[(size_t)s3 * OUT_DIM + lane]) << 16);
        acc += v0 * m0 + v1 * m1 + v2 * m2 + v3 * m3;
    }
    for (; j < n; ++j) {
        int s = __shfl(sj, j);
        float nm = __shfl(nmj, j);
        acc += __uint_as_float(((uint_t)h2[(size_t)s * OUT_DIM + lane]) << 16) * nm;
    }
    out[(size_t)i * OUT_DIM + lane] = acc + b[lane];
}

extern "C" void kernel_launch(void* const* d_in, const int* in_sizes, int n_in,
                              void* d_out, int out_size, void* d_ws, size_t ws_size,
                              hipStream_t stream) {
    const float* x   = (const float*)d_in[0];
    const int*   ei  = (const int*)d_in[1];    // [2, E] int32
    const float* W1  = (const float*)d_in[2];
    const float* b1  = (const float*)d_in[3];
    const float* W2  = (const float*)d_in[4];
    const float* b2  = (const float*)d_in[5];
    float* out = (float*)d_out;

    const int* srcs = ei;             // edge_index[0]
    const int* dsts = ei + N_EDGES;   // edge_index[1]

    // workspace (~43 MB)
    char* ws = (char*)d_ws;
    size_t o = 0;
    auto alloc = [&](size_t bytes) { void* p = ws + o; o = (o + bytes + 511) & ~size_t(511); return p; };
    int*      bin_cur = (int*)   alloc(K_BINS * 4);
    float*    dinv  = (float*)   alloc(N_NODES * 4);
    int*      ndeg  = (int*)     alloc(N_NODES * 4);
    ushort_t* es    = (ushort_t*)alloc((size_t)K_BINS * NPB * CAP * 2);  // padded to 50176 nodes
    uint_t*   binbuf= (uint_t*)  alloc((size_t)K_BINS * BINCAP * 4);     // 4 MB
    ushort_t* w1t   = (ushort_t*)alloc((size_t)IN_DIM * HID_DIM * 2);
    ushort_t* w2t   = (ushort_t*)alloc((size_t)HID_DIM * OUT_DIM * 2);
    ushort_t* hb    = (ushort_t*)alloc((size_t)N_NODES * HID_DIM * 2);
    ushort_t* hrelu = (ushort_t*)alloc((size_t)N_NODES * HID_DIM * 2);
    ushort_t* h2    = (ushort_t*)alloc((size_t)N_NODES * OUT_DIM * 2);

    hipMemsetAsync(bin_cur, 0, K_BINS * 4, stream);
    k_init  <<<160, 256, 0, stream>>>(W1, w1t, W2, w2t);
    k_bin   <<<N_BINWG, 256, 0, stream>>>(srcs, dsts, bin_cur, binbuf);
    k_fill  <<<K_BINS, 256, 0, stream>>>(bin_cur, binbuf, es, dinv, ndeg);
    k_gemm1 <<<N_NODES / 16, 64, 0, stream>>>(x, w1t, hb);
    k_agg1  <<<N_NODES / 4, 256, 0, stream>>>(hb, ndeg, dinv, es, b1, hrelu);
    k_gemm2 <<<N_NODES / 16, 64, 0, stream>>>(hrelu, w2t, h2);
    k_agg2  <<<N_NODES / 4, 256, 0, stream>>>(h2, ndeg, dinv, es, b2, out);
}